// Round 12
// baseline (274.469 us; speedup 1.0000x reference)
//
#include <hip/hip_runtime.h>
#include <math.h>

#define NSRC 80000
#define NTGT 20000
#define NE   80000
#define NI   129       // intervals = EH breakpoints + 1
#define CHUNK 16       // edges gathered per wave batch in k_ut
#define H0B  1250      // h0 blocks inside k_front
#define CLB  313       // class blocks inside k_front
#define WTB  36        // weight-transpose blocks inside k_front (9216 float4)

// ---------------- workspace layout (bytes) ----------------
constexpr size_t H0_OFF   = 0;                                    // 80000*64 f32
constexpr size_t MC_OFF   = H0_OFF + (size_t)NSRC*64*4;           // 2 slots * (M4096 + C4096)
constexpr size_t AGG_OFF  = MC_OFF + 16384*4;                     // (unused after fusion)
constexpr size_t CNT_OFF  = AGG_OFF + (size_t)NTGT*64*4;          // 20000 f32 [zeroed]
constexpr size_t BINS_OFF = CNT_OFF + (size_t)NTGT*4;             // 132 int   [zeroed]
constexpr size_t ZERO_BYTES = (BINS_OFF + 132*4) - CNT_OFF;
constexpr size_t HDR_OFF  = BINS_OFF + 132*4;                     // j0, j1, nlive
constexpr size_t DOFF_OFF = HDR_OFF + 64;                         // 20001 int (padded)
constexpr size_t DCUR_OFF = DOFF_OFF + 20004*4;                   // 20000 int
constexpr size_t JBUF_OFF = DCUR_OFF + 20000*4;                   // 80000 int
constexpr size_t WBUF_OFF = JBUF_OFF + (size_t)NE*4;              // 80000 f32
constexpr size_t PSRC_OFF = WBUF_OFF + (size_t)NE*4;              // 80000+64 int (src | slot<<31)
constexpr size_t PW_OFF   = PSRC_OFF + (size_t)(NE+64)*4;         // 80000+64 f32
constexpr size_t WT_OFF   = PW_OFF + (size_t)(NE+64)*4;           // 9216 float4 transposed weights

typedef float v2f __attribute__((ext_vector_type(2)));

__device__ __forceinline__ float frcp_(float x){ return __builtin_amdgcn_rcpf(x); }
__device__ __forceinline__ float sigm_(float x){ return frcp_(1.0f + __expf(-x)); }
__device__ __forceinline__ float tanhf_(float x){ return 1.0f - 2.0f*frcp_(1.0f + __expf(2.0f*x)); }
__device__ __forceinline__ float rl_(float v, int i){
  return __int_as_float(__builtin_amdgcn_readlane(__float_as_int(v), i));
}
__device__ __forceinline__ int rli_(int v, int i){
  return __builtin_amdgcn_readlane(v, i);
}
// pack lanes (i, i+1) of per-lane value v into one SGPR pair (SALU-only pack)
__device__ __forceinline__ unsigned long long bpack_(float v, int i){
  unsigned a = (unsigned)__builtin_amdgcn_readlane(__float_as_int(v), i);
  unsigned b = (unsigned)__builtin_amdgcn_readlane(__float_as_int(v), i+1);
  return (unsigned long long)a | ((unsigned long long)b << 32);
}
// packed fp32 fma: c = {s.lo,s.hi} * b + c  (scalar-pair src0 = 1 SGPR read, legal)
__device__ __forceinline__ void pkfma_(v2f& c, unsigned long long s, v2f b){
  asm("v_pk_fma_f32 %0, %1, %2, %0" : "+v"(c) : "s"(s), "v"(b));
}
// async gather of one 256B row into wave-uniform LDS base.
// global address is PER-LANE (lane i passes g+i); LDS dest = uniform base + lane*4.
__device__ __forceinline__ void gl_lds4(const float* g, float* l){
  __builtin_amdgcn_global_load_lds((const __attribute__((address_space(1))) void*)g,
                                   (__attribute__((address_space(3))) void*)l, 4, 0, 0);
}

// ---------------- K1: fused front = [h0 GEMM | edge-classify | weight-transpose] --------
// R6 VERBATIM — proven-best front.
__global__ __launch_bounds__(256) void k_front(const float* __restrict__ x,
    const float* __restrict__ W0, const float* __restrict__ b0, float* __restrict__ h0,
    const int* __restrict__ eids, const int* __restrict__ edst, const float* __restrict__ ew,
    const float* __restrict__ A1, const float* __restrict__ c1,
    int* __restrict__ jbuf, float* __restrict__ wbuf,
    int* __restrict__ bins, float* __restrict__ counts,
    const float* __restrict__ Wr_g, const float* __restrict__ Wih,
    const float* __restrict__ Whh, const float* __restrict__ W1,
    const float* __restrict__ W2, float4* __restrict__ wt) {
  __shared__ float sh[64*132];
  const int tid = threadIdx.x;
  if (blockIdx.x < H0B) {
    // ---- h0 path ----
    {
      const float4* src = (const float4*)W0;
#pragma unroll
      for (int q = 0; q < 8; q++) {
        int p4 = q*256 + tid;
        int o = p4 >> 5, k4 = p4 & 31;
        *(float4*)&sh[o*132 + k4*4] = src[p4];
      }
    }
    __syncthreads();
    const int wid = tid >> 6, lane = tid & 63;
    const int rg = lane >> 3, og = lane & 7;
    const int r0 = blockIdx.x*64 + wid*16 + rg*2;
    float acc[2][8];
#pragma unroll
    for (int a = 0; a < 2; a++)
#pragma unroll
      for (int b = 0; b < 8; b++) acc[a][b] = 0.0f;
#pragma unroll 4
    for (int iq = 0; iq < 32; iq++) {
      float4 xv[2], wv[8];
#pragma unroll
      for (int a = 0; a < 2; a++) xv[a] = *(const float4*)(x + (size_t)(r0+a)*128 + iq*4);
#pragma unroll
      for (int b = 0; b < 8; b++) wv[b] = *(const float4*)&sh[(og + 8*b)*132 + iq*4];
#pragma unroll
      for (int a = 0; a < 2; a++)
#pragma unroll
        for (int b = 0; b < 8; b++) {
          acc[a][b] = fmaf(xv[a].x, wv[b].x, acc[a][b]);
          acc[a][b] = fmaf(xv[a].y, wv[b].y, acc[a][b]);
          acc[a][b] = fmaf(xv[a].z, wv[b].z, acc[a][b]);
          acc[a][b] = fmaf(xv[a].w, wv[b].w, acc[a][b]);
        }
    }
    float bv[8];
#pragma unroll
    for (int b = 0; b < 8; b++) bv[b] = b0[og + 8*b];
#pragma unroll
    for (int a = 0; a < 2; a++)
#pragma unroll
      for (int b = 0; b < 8; b++)
        h0[(size_t)(r0+a)*64 + og + 8*b] = fmaxf(acc[a][b] + bv[b], 0.0f);
  } else if (blockIdx.x < H0B + CLB) {
    // ---- class path: local breakpoint sort + classify ----
    float* ts = sh;                 // 128 f32
    int*   lb = (int*)(sh + 128);   // NI ints
    if (tid < 128) {
      float a = A1[tid], c = c1[tid];
      ts[tid] = (a != 0.0f) ? (-c / a) : INFINITY;
    }
    for (int j = tid; j < NI; j += 256) lb[j] = 0;
    __syncthreads();
    for (int ks = 2; ks <= 128; ks <<= 1) {
      for (int j = ks >> 1; j > 0; j >>= 1) {
        if (tid < 128) {
          int ixj = tid ^ j;
          if (ixj > tid) {
            float va = ts[tid], vb = ts[ixj];
            bool asc = ((tid & ks) == 0);
            if (asc ? (va > vb) : (va < vb)) { ts[tid] = vb; ts[ixj] = va; }
          }
        }
        __syncthreads();
      }
    }
    int e = (blockIdx.x - H0B)*256 + tid;
    if (e < NE) {
      float w = ew[eids[e]];
      int lo = 0, hi = 128;
      while (lo < hi) { int mid = (lo+hi)>>1; if (ts[mid] < w) lo = mid+1; else hi = mid; }
      jbuf[e] = lo; wbuf[e] = w;
      atomicAdd(&lb[lo], 1);
      atomicAdd(&counts[edst[e]], 1.0f);
    }
    __syncthreads();
    for (int j = tid; j < NI; j += 256) if (lb[j] > 0) atomicAdd(&bins[j], lb[j]);
  } else {
    // ---- weight-transpose path ----
    int p = (blockIdx.x - (H0B + CLB))*256 + tid;   // 0..9215
    float4 v;
    if (p < 1024) {
      int iq = p >> 6, o = p & 63;
      v.x = Wr_g[(4*iq+0)*64 + o];
      v.y = Wr_g[(4*iq+1)*64 + o];
      v.z = Wr_g[(4*iq+2)*64 + o];
      v.w = Wr_g[(4*iq+3)*64 + o];
    } else if (p < 4096) {
      int q = p - 1024; int g = q >> 10, iq = (q >> 6) & 15, o = q & 63;
      v = ((const float4*)Wih)[(g*64 + o)*16 + iq];
    } else if (p < 7168) {
      int q = p - 4096; int g = q >> 10, iq = (q >> 6) & 15, o = q & 63;
      v = ((const float4*)Whh)[(g*64 + o)*16 + iq];
    } else if (p < 8192) {
      int q = p - 7168; int iq = q >> 6, o = q & 63;
      v = ((const float4*)W1)[o*16 + iq];
    } else {
      int q = p - 8192; int iq = q >> 6, o = q & 63;
      v = ((const float4*)W2)[o*16 + iq];
    }
    wt[p] = v;
  }
}

// ---------------- K2: [plan (block 0, 1024-thr VERBATIM) | M/C build (blocks 1..8)] -----
// Fuses the R6 k_plan (1024 threads — R9 lesson: do NOT shrink it) with the mc path so
// they overlap in one launch. mc blocks compute j0/j1 inline from bins (proven in R9);
// 1024 threads/block, 4 chunks each (blocks 1-4: slot 0, blocks 5-8: slot 1).
__global__ __launch_bounds__(1024) void k_pm(const float* __restrict__ counts,
    const int* __restrict__ bins, int* __restrict__ doffs, int* __restrict__ dcur,
    int* __restrict__ hdr, const float* __restrict__ A1, const float* __restrict__ c1,
    const float* __restrict__ A2, const float* __restrict__ c2, float* __restrict__ MC) {
  __shared__ int part[1024];
  __shared__ float tt[128], sk[128], uk[128];
  __shared__ int m0s, m1s, nls;
  const int t = threadIdx.x;
  if (blockIdx.x == 0) {
    // ---- plan path (R6 k_plan body verbatim) ----
    const int base = t*20;
    int s = 0;
    if (base < NTGT)
      for (int q = 0; q < 20 && base+q < NTGT; q++) s += (int)counts[base+q];
    part[t] = s;
    if (t == 0) { m0s = 999; m1s = 999; nls = 0; }
    __syncthreads();
    if (t < NI && bins[t] > 0) { atomicMin(&m0s, t); atomicAdd(&nls, 1); }
    for (int off = 1; off < 1024; off <<= 1) {
      int v = (t >= off) ? part[t-off] : 0;
      __syncthreads();
      part[t] += v;
      __syncthreads();
    }
    if (t < NI && bins[t] > 0 && t != m0s) atomicMin(&m1s, t);
    int run = part[t] - s;
    if (base < NTGT)
      for (int q = 0; q < 20 && base+q < NTGT; q++) {
        int c = (int)counts[base+q];
        doffs[base+q] = run; dcur[base+q] = run;
        run += c;
      }
    __syncthreads();
    if (t == 0) {
      doffs[NTGT] = NE;
      hdr[0] = m0s;
      hdr[1] = (m1s == 999) ? -1 : m1s;
      hdr[2] = nls;
    }
  } else {
    // ---- mc path: inline j0/j1 from bins, then T sort + M/C chunk ----
    if (t == 0) { m0s = 999; m1s = 999; }
    __syncthreads();
    if (t < NI && bins[t] > 0) atomicMin(&m0s, t);
    __syncthreads();
    if (t < NI && bins[t] > 0 && t != m0s) atomicMin(&m1s, t);
    __syncthreads();
    const int q = (blockIdx.x - 1)*1024 + t;   // 0..8191; 1024 | 4096 so s uniform/block
    const int s = q >> 12;
    const int pp = q & 4095;
    const int j = (s == 0) ? m0s : ((m1s == 999) ? -1 : m1s);
    if (j < 0 || j > 128) return;    // uniform per block
    if (t < 128) {
      float a = A1[t], c = c1[t];
      tt[t] = (a != 0.0f) ? (-c / a) : INFINITY;
    }
    __syncthreads();
    for (int ks = 2; ks <= 128; ks <<= 1) {
      for (int jj = ks >> 1; jj > 0; jj >>= 1) {
        if (t < 128) {
          int ixj = t ^ jj;
          if (ixj > t) {
            float va = tt[t], vb = tt[ixj];
            bool asc = ((t & ks) == 0);
            if (asc ? (va > vb) : (va < vb)) { tt[t] = vb; tt[ixj] = va; }
          }
        }
        __syncthreads();
      }
    }
    float lo = (j > 0)   ? tt[j-1] : -INFINITY;
    float hi = (j < 128) ? tt[j]   :  INFINITY;
    float rj;
    if (isinf(lo) && isinf(hi)) rj = 0.0f;
    else if (isinf(lo)) rj = hi - 1.0f;
    else if (isinf(hi)) rj = lo + 1.0f;
    else rj = 0.5f*(lo + hi);
    if (t < 128) {
      float a = A1[t], c = c1[t];
      bool act = (rj*a + c) > 0.0f;
      sk[t] = act ? a : 0.0f;
      uk[t] = act ? c : 0.0f;
    }
    __syncthreads();
    float* M = MC + (size_t)s*8192;
    float* C = M + 4096;
    const float4* a2p = (const float4*)(A2 + (size_t)pp*128);
    float accM = 0.0f, accC = 0.0f;
#pragma unroll 8
    for (int qq = 0; qq < 32; qq++) {
      float4 v = a2p[qq];
      int k4 = qq*4;
      accM += sk[k4]*v.x + sk[k4+1]*v.y + sk[k4+2]*v.z + sk[k4+3]*v.w;
      accC += uk[k4]*v.x + uk[k4+1]*v.y + uk[k4+2]*v.z + uk[k4+3]*v.w;
    }
    M[pp] = accM;
    C[pp] = accC + c2[pp];
  }
}

// ---------------- K3: dst-sort scatter (313 blocks, R9-proven) --------------------------
__global__ __launch_bounds__(256) void k_scat(const int* __restrict__ hdr,
    const int* __restrict__ esrc, const int* __restrict__ edst,
    const int* __restrict__ jbuf, const float* __restrict__ wbuf,
    int* __restrict__ dcur, int* __restrict__ psrc, float* __restrict__ pw) {
  int e = blockIdx.x*256 + threadIdx.x;
  if (e >= NE) return;
  int j0 = hdr[0];
  int d = edst[e];
  int pos = atomicAdd(&dcur[d], 1);
  int s = (jbuf[e] == j0) ? 0 : 1;
  psrc[pos] = esrc[e] | (s << 31);
  pw[pos] = wbuf[e];
}

// ---------------- K4: FUSED uvagg + tail (R6/R10 VERBATIM — proven 108us, VGPR 32) ------
// Tile sweep complete: 8/wave=110(R6-era tail), 4/wave=108 (optimum), 2/wave=119 (R11:
// shared weight-load overhead doubles past TLP saturation). Keep 4 dsts/wave.
// DO NOT replace the readlane/bpack broadcasts with LDS or VGPR temps: R4 and R7 both
// proved that variant hits a catastrophic scratch-spill cliff (400+ MB scratch traffic).
__global__ __launch_bounds__(256, 4) void k_ut(const int* __restrict__ doffs,
    const int* __restrict__ psrc, const float* __restrict__ pw,
    const float* __restrict__ MCg, const float* __restrict__ h0,
    const float4* __restrict__ wt, const float* __restrict__ bconv,
    const float* __restrict__ bih, const float* __restrict__ bhh,
    const float* __restrict__ b1, const float* __restrict__ b2,
    float* __restrict__ out) {
  __shared__ float rows_all[4][CHUNK*64];
  const int tid = threadIdx.x;
  const int lane = tid & 63;
  const int wid = __builtin_amdgcn_readfirstlane(tid >> 6);
  float* rows = &rows_all[wid][0];
  const int tb = __builtin_amdgcn_readfirstlane(blockIdx.x*16 + wid*4);
  const int o = lane;

  int b[5];
#pragma unroll
  for (int t = 0; t <= 4; t++) b[t] = doffs[tb + t];   // uniform -> s_load

  // issue tail-phase h rows early; in flight under the gather phase
  float h[4];
#pragma unroll
  for (int t = 0; t < 4; t++) h[t] = h0[(size_t)(tb+t)*64 + o];

  // ---------------- phase 1: U/V edge accumulate ----------------
  float U0[4], V0[4], U1[4], V1[4];
#pragma unroll
  for (int t = 0; t < 4; t++) { U0[t]=0.f; V0[t]=0.f; U1[t]=0.f; V1[t]=0.f; }

  const int e0 = b[0], e4 = b[4];
  for (int c0 = e0; c0 < e4; c0 += CHUNK) {
    const int n = min(CHUNK, e4 - c0);
    int   psv = psrc[c0 + (lane & (CHUNK-1))];
    float pwv = pw  [c0 + (lane & (CHUNK-1))];
    // one 256B global->LDS DMA per edge; PER-LANE global addr (+lane)
    for (int k = 0; k < n; k++) {
      int src = rli_(psv, k) & 0x7fffffff;
      gl_lds4(h0 + (size_t)src*64 + lane, rows + k*64);
    }
    __builtin_amdgcn_s_waitcnt(0);
#pragma unroll
    for (int t = 0; t < 4; t++) {
      int lo = b[t] > c0 ? b[t] : c0;
      int hi = b[t+1] < c0+n ? b[t+1] : c0+n;
      for (int pos = lo; pos < hi; pos++) {
        int k = pos - c0;
        int ps = rli_(psv, k);
        float w = rl_(pwv, k);
        float v = rows[k*64 + lane];
        if (ps >= 0) { U0[t] = fmaf(w, v, U0[t]); V0[t] += v; }
        else         { U1[t] = fmaf(w, v, U1[t]); V1[t] += v; }
      }
    }
  }
  float a[4];
#pragma unroll
  for (int t = 0; t < 4; t++) a[t] = 0.f;
#pragma unroll 4
  for (int i = 0; i < 64; i++) {
    float m0 = MCg[i*64 + lane];
    float c0 = MCg[4096 + i*64 + lane];
    float m1 = MCg[8192 + i*64 + lane];
    float cc1 = MCg[12288 + i*64 + lane];
#pragma unroll
    for (int t = 0; t < 4; t++) {
      a[t] = fmaf(rl_(U0[t], i), m0, a[t]);
      a[t] = fmaf(rl_(V0[t], i), c0, a[t]);
      a[t] = fmaf(rl_(U1[t], i), m1, a[t]);
      a[t] = fmaf(rl_(V1[t], i), cc1, a[t]);
    }
  }

  // ---------------- phase 2: conv-root + GRU(3) + MLP (R5 body) ----------------
  const float4* __restrict__ WrT  = wt;          // [16][64]
  const float4* __restrict__ WihT = wt + 1024;   // [3][16][64]
  const float4* __restrict__ WhhT = wt + 4096;   // [3][16][64]
  const float4* __restrict__ W1T  = wt + 7168;   // [16][64]
  const float4* __restrict__ W2T  = wt + 8192;   // [16][64]

  // ---- m = relu(a/c + h @ Wr + bc) ----
  float m[4];
  {
    v2f acc[4];
    const float bc = bconv[o];
#pragma unroll
    for (int t = 0; t < 4; t++) {
      float c = fmaxf((float)(b[t+1] - b[t]), 1.0f);
      acc[t].x = a[t] / c + bc;
      acc[t].y = 0.0f;
    }
    for (int iq = 0; iq < 16; iq++) {
      float4 wv = WrT[iq*64 + o];
      v2f wlo = { wv.x, wv.y }, whi = { wv.z, wv.w };
      int i4 = iq*4;
#pragma unroll
      for (int t = 0; t < 4; t++) {
        unsigned long long slo = bpack_(h[t], i4);
        unsigned long long shi = bpack_(h[t], i4+2);
        pkfma_(acc[t], slo, wlo);
        pkfma_(acc[t], shi, whi);
      }
    }
#pragma unroll
    for (int t = 0; t < 4; t++) m[t] = fmaxf(acc[t].x + acc[t].y, 0.0f);
  }

  // ---- gi = m @ Wih + (bih [+bhh folded for gates 0,1]) ----
  float gi0[4], gi1[4], gi2[4];
  {
    v2f a0[4], a1[4], a2[4];
#pragma unroll
    for (int t = 0; t < 4; t++) {
      a0[t].x = 0.0f; a0[t].y = 0.0f;
      a1[t].x = 0.0f; a1[t].y = 0.0f;
      a2[t].x = 0.0f; a2[t].y = 0.0f;
    }
    for (int iq = 0; iq < 16; iq++) {
      float4 w0 = WihT[iq*64 + o];
      float4 w1 = WihT[(16+iq)*64 + o];
      float4 w2 = WihT[(32+iq)*64 + o];
      v2f w0lo = { w0.x, w0.y }, w0hi = { w0.z, w0.w };
      v2f w1lo = { w1.x, w1.y }, w1hi = { w1.z, w1.w };
      v2f w2lo = { w2.x, w2.y }, w2hi = { w2.z, w2.w };
      int i4 = iq*4;
#pragma unroll
      for (int t = 0; t < 4; t++) {
        unsigned long long slo = bpack_(m[t], i4);
        unsigned long long shi = bpack_(m[t], i4+2);
        pkfma_(a0[t], slo, w0lo); pkfma_(a0[t], shi, w0hi);
        pkfma_(a1[t], slo, w1lo); pkfma_(a1[t], shi, w1hi);
        pkfma_(a2[t], slo, w2lo); pkfma_(a2[t], shi, w2hi);
      }
    }
    const float bi0 = bih[o]      + bhh[o];
    const float bi1 = bih[64+o]   + bhh[64+o];
    const float bi2 = bih[128+o];
#pragma unroll
    for (int t = 0; t < 4; t++) {
      gi0[t] = bi0 + a0[t].x + a0[t].y;
      gi1[t] = bi1 + a1[t].x + a1[t].y;
      gi2[t] = bi2 + a2[t].x + a2[t].y;
    }
  }

  // ---- GRU(3) ----
  const float bh2 = bhh[128+o];
#pragma unroll 1
  for (int step = 0; step < 3; step++) {
    v2f a0[4], a1[4], a2[4];
#pragma unroll
    for (int t = 0; t < 4; t++) {
      a0[t].x = 0.0f; a0[t].y = 0.0f;
      a1[t].x = 0.0f; a1[t].y = 0.0f;
      a2[t].x = 0.0f; a2[t].y = 0.0f;
    }
    for (int iq = 0; iq < 16; iq++) {
      float4 w0 = WhhT[iq*64 + o];
      float4 w1 = WhhT[(16+iq)*64 + o];
      float4 w2 = WhhT[(32+iq)*64 + o];
      v2f w0lo = { w0.x, w0.y }, w0hi = { w0.z, w0.w };
      v2f w1lo = { w1.x, w1.y }, w1hi = { w1.z, w1.w };
      v2f w2lo = { w2.x, w2.y }, w2hi = { w2.z, w2.w };
      int i4 = iq*4;
#pragma unroll
      for (int t = 0; t < 4; t++) {
        unsigned long long slo = bpack_(h[t], i4);
        unsigned long long shi = bpack_(h[t], i4+2);
        pkfma_(a0[t], slo, w0lo); pkfma_(a0[t], shi, w0hi);
        pkfma_(a1[t], slo, w1lo); pkfma_(a1[t], shi, w1hi);
        pkfma_(a2[t], slo, w2lo); pkfma_(a2[t], shi, w2hi);
      }
    }
#pragma unroll
    for (int t = 0; t < 4; t++) {
      float r = sigm_(gi0[t] + a0[t].x + a0[t].y);
      float z = sigm_(gi1[t] + a1[t].x + a1[t].y);
      float g2s = bh2 + a2[t].x + a2[t].y;
      float n = tanhf_(fmaf(r, g2s, gi2[t]));
      h[t] = fmaf(z, h[t] - n, n);
    }
  }

  // ---- o1 = relu(h @ W1 + b1) ----
  float o1[4];
  {
    v2f acc[4];
#pragma unroll
    for (int t = 0; t < 4; t++) { acc[t].x = 0.0f; acc[t].y = 0.0f; }
    for (int iq = 0; iq < 16; iq++) {
      float4 wv = W1T[iq*64 + o];
      v2f wlo = { wv.x, wv.y }, whi = { wv.z, wv.w };
      int i4 = iq*4;
#pragma unroll
      for (int t = 0; t < 4; t++) {
        unsigned long long slo = bpack_(h[t], i4);
        unsigned long long shi = bpack_(h[t], i4+2);
        pkfma_(acc[t], slo, wlo);
        pkfma_(acc[t], shi, whi);
      }
    }
    const float bb = b1[o];
#pragma unroll
    for (int t = 0; t < 4; t++) o1[t] = fmaxf(bb + acc[t].x + acc[t].y, 0.0f);
  }

  // ---- out = o1 @ W2 + b2 ----
  {
    v2f acc[4];
#pragma unroll
    for (int t = 0; t < 4; t++) { acc[t].x = 0.0f; acc[t].y = 0.0f; }
    for (int iq = 0; iq < 16; iq++) {
      float4 wv = W2T[iq*64 + o];
      v2f wlo = { wv.x, wv.y }, whi = { wv.z, wv.w };
      int i4 = iq*4;
#pragma unroll
      for (int t = 0; t < 4; t++) {
        unsigned long long slo = bpack_(o1[t], i4);
        unsigned long long shi = bpack_(o1[t], i4+2);
        pkfma_(acc[t], slo, wlo);
        pkfma_(acc[t], shi, whi);
      }
    }
    const float bb = b2[o];
#pragma unroll
    for (int t = 0; t < 4; t++) out[(size_t)(tb+t)*64 + o] = bb + acc[t].x + acc[t].y;
  }
}

extern "C" void kernel_launch(void* const* d_in, const int* in_sizes, int n_in,
                              void* d_out, int out_size, void* d_ws, size_t ws_size,
                              hipStream_t stream) {
  const float* x    = (const float*)d_in[0];
  const int*   esrc = (const int*)d_in[2];
  const int*   edst = (const int*)d_in[3];
  const int*   eids = (const int*)d_in[4];
  const float* ew   = (const float*)d_in[5];
  const float* W0   = (const float*)d_in[6];
  const float* b0   = (const float*)d_in[7];
  const float* A1   = (const float*)d_in[8];
  const float* c1   = (const float*)d_in[9];
  const float* A2   = (const float*)d_in[10];
  const float* c2   = (const float*)d_in[11];
  const float* Wr   = (const float*)d_in[12];
  const float* bcv  = (const float*)d_in[13];
  const float* Wih  = (const float*)d_in[14];
  const float* Whh  = (const float*)d_in[15];
  const float* bih  = (const float*)d_in[16];
  const float* bhh  = (const float*)d_in[17];
  const float* W1   = (const float*)d_in[18];
  const float* b1   = (const float*)d_in[19];
  const float* W2   = (const float*)d_in[20];
  const float* b2   = (const float*)d_in[21];

  char* ws = (char*)d_ws;
  float* h0    = (float*)(ws + H0_OFF);
  float* MC    = (float*)(ws + MC_OFF);
  float* cnts  = (float*)(ws + CNT_OFF);
  int*   bins  = (int*)(ws + BINS_OFF);
  int*   hdr   = (int*)(ws + HDR_OFF);
  int*   doffs = (int*)(ws + DOFF_OFF);
  int*   dcur  = (int*)(ws + DCUR_OFF);
  int*   jbuf  = (int*)(ws + JBUF_OFF);
  float* wbuf  = (float*)(ws + WBUF_OFF);
  int*   psrc  = (int*)(ws + PSRC_OFF);
  float* pw    = (float*)(ws + PW_OFF);
  float4* wt   = (float4*)(ws + WT_OFF);

  hipMemsetAsync(ws + CNT_OFF, 0, ZERO_BYTES, stream);
  k_front <<<H0B + CLB + WTB, 256, 0, stream>>>(x, W0, b0, h0, eids, edst, ew, A1, c1,
                                                jbuf, wbuf, bins, cnts,
                                                Wr, Wih, Whh, W1, W2, wt);
  k_pm    <<<9, 1024, 0, stream>>>(cnts, bins, doffs, dcur, hdr, A1, c1, A2, c2, MC);
  k_scat  <<<CLB, 256, 0, stream>>>(hdr, esrc, edst, jbuf, wbuf, dcur, psrc, pw);
  k_ut    <<<1250, 256, 0, stream>>>(doffs, psrc, pw, MC, h0, wt, bcv,
                                     bih, bhh, b1, b2, (float*)d_out);
}

// Round 14
// 262.746 us; speedup vs baseline: 1.0446x; 1.0446x over previous
//
#include <hip/hip_runtime.h>
#include <math.h>

#define NSRC 80000
#define NTGT 20000
#define NE   80000
#define NI   129       // intervals = EH breakpoints + 1
#define CHUNK 16       // edges gathered per wave batch in k_ut
#define H0B  1250      // h0 blocks inside k_front
#define CLB  313       // class blocks inside k_front
#define WTB  36        // weight-transpose blocks inside k_front (9216 float4)

// ---------------- workspace layout (bytes) ----------------
constexpr size_t H0_OFF   = 0;                                    // 80000*64 f32
constexpr size_t MC_OFF   = H0_OFF + (size_t)NSRC*64*4;           // 2 slots * (M4096 + C4096)
constexpr size_t AGG_OFF  = MC_OFF + 16384*4;                     // (unused after fusion)
constexpr size_t CNT_OFF  = AGG_OFF + (size_t)NTGT*64*4;          // 20000 f32 [zeroed]
constexpr size_t BINS_OFF = CNT_OFF + (size_t)NTGT*4;             // 132 int   [zeroed]
constexpr size_t ZERO_BYTES = (BINS_OFF + 132*4) - CNT_OFF;
constexpr size_t HDR_OFF  = BINS_OFF + 132*4;                     // j0, j1, nlive
constexpr size_t DOFF_OFF = HDR_OFF + 64;                         // 20001 int (padded)
constexpr size_t DCUR_OFF = DOFF_OFF + 20004*4;                   // 20000 int
constexpr size_t JBUF_OFF = DCUR_OFF + 20000*4;                   // 80000 int
constexpr size_t WBUF_OFF = JBUF_OFF + (size_t)NE*4;              // 80000 f32
constexpr size_t PSRC_OFF = WBUF_OFF + (size_t)NE*4;              // 80000+64 int (src | slot<<31)
constexpr size_t PW_OFF   = PSRC_OFF + (size_t)(NE+64)*4;         // 80000+64 f32
constexpr size_t WT_OFF   = PW_OFF + (size_t)(NE+64)*4;           // 9216 float4 transposed weights

typedef float v2f __attribute__((ext_vector_type(2)));

__device__ __forceinline__ float frcp_(float x){ return __builtin_amdgcn_rcpf(x); }
__device__ __forceinline__ float sigm_(float x){ return frcp_(1.0f + __expf(-x)); }
__device__ __forceinline__ float tanhf_(float x){ return 1.0f - 2.0f*frcp_(1.0f + __expf(2.0f*x)); }
__device__ __forceinline__ float rl_(float v, int i){
  return __int_as_float(__builtin_amdgcn_readlane(__float_as_int(v), i));
}
__device__ __forceinline__ int rli_(int v, int i){
  return __builtin_amdgcn_readlane(v, i);
}
// pack lanes (i, i+1) of per-lane value v into one SGPR pair (SALU-only pack)
__device__ __forceinline__ unsigned long long bpack_(float v, int i){
  unsigned a = (unsigned)__builtin_amdgcn_readlane(__float_as_int(v), i);
  unsigned b = (unsigned)__builtin_amdgcn_readlane(__float_as_int(v), i+1);
  return (unsigned long long)a | ((unsigned long long)b << 32);
}
// packed fp32 fma: c = {s.lo,s.hi} * b + c  (scalar-pair src0 = 1 SGPR read, legal)
__device__ __forceinline__ void pkfma_(v2f& c, unsigned long long s, v2f b){
  asm("v_pk_fma_f32 %0, %1, %2, %0" : "+v"(c) : "s"(s), "v"(b));
}
// async gather of one 256B row into wave-uniform LDS base.
// global address is PER-LANE (lane i passes g+i); LDS dest = uniform base + lane*4.
__device__ __forceinline__ void gl_lds4(const float* g, float* l){
  __builtin_amdgcn_global_load_lds((const __attribute__((address_space(1))) void*)g,
                                   (__attribute__((address_space(3))) void*)l, 4, 0, 0);
}

// ---------------- K1: fused front = [h0 GEMM | edge-classify | weight-transpose] --------
// PROVEN-BEST (R6/R10). R8/R9/R12 lessons: do NOT carve h0 blocks out, do NOT shrink
// the 1024-thread plan, do NOT regroup plan/mc/scatter — all regressed.
__global__ __launch_bounds__(256) void k_front(const float* __restrict__ x,
    const float* __restrict__ W0, const float* __restrict__ b0, float* __restrict__ h0,
    const int* __restrict__ eids, const int* __restrict__ edst, const float* __restrict__ ew,
    const float* __restrict__ A1, const float* __restrict__ c1,
    int* __restrict__ jbuf, float* __restrict__ wbuf,
    int* __restrict__ bins, float* __restrict__ counts,
    const float* __restrict__ Wr_g, const float* __restrict__ Wih,
    const float* __restrict__ Whh, const float* __restrict__ W1,
    const float* __restrict__ W2, float4* __restrict__ wt) {
  __shared__ float sh[64*132];
  const int tid = threadIdx.x;
  if (blockIdx.x < H0B) {
    // ---- h0 path ----
    {
      const float4* src = (const float4*)W0;
#pragma unroll
      for (int q = 0; q < 8; q++) {
        int p4 = q*256 + tid;
        int o = p4 >> 5, k4 = p4 & 31;
        *(float4*)&sh[o*132 + k4*4] = src[p4];
      }
    }
    __syncthreads();
    const int wid = tid >> 6, lane = tid & 63;
    const int rg = lane >> 3, og = lane & 7;
    const int r0 = blockIdx.x*64 + wid*16 + rg*2;
    float acc[2][8];
#pragma unroll
    for (int a = 0; a < 2; a++)
#pragma unroll
      for (int b = 0; b < 8; b++) acc[a][b] = 0.0f;
#pragma unroll 4
    for (int iq = 0; iq < 32; iq++) {
      float4 xv[2], wv[8];
#pragma unroll
      for (int a = 0; a < 2; a++) xv[a] = *(const float4*)(x + (size_t)(r0+a)*128 + iq*4);
#pragma unroll
      for (int b = 0; b < 8; b++) wv[b] = *(const float4*)&sh[(og + 8*b)*132 + iq*4];
#pragma unroll
      for (int a = 0; a < 2; a++)
#pragma unroll
        for (int b = 0; b < 8; b++) {
          acc[a][b] = fmaf(xv[a].x, wv[b].x, acc[a][b]);
          acc[a][b] = fmaf(xv[a].y, wv[b].y, acc[a][b]);
          acc[a][b] = fmaf(xv[a].z, wv[b].z, acc[a][b]);
          acc[a][b] = fmaf(xv[a].w, wv[b].w, acc[a][b]);
        }
    }
    float bv[8];
#pragma unroll
    for (int b = 0; b < 8; b++) bv[b] = b0[og + 8*b];
#pragma unroll
    for (int a = 0; a < 2; a++)
#pragma unroll
      for (int b = 0; b < 8; b++)
        h0[(size_t)(r0+a)*64 + og + 8*b] = fmaxf(acc[a][b] + bv[b], 0.0f);
  } else if (blockIdx.x < H0B + CLB) {
    // ---- class path: local breakpoint sort + classify ----
    float* ts = sh;                 // 128 f32
    int*   lb = (int*)(sh + 128);   // NI ints
    if (tid < 128) {
      float a = A1[tid], c = c1[tid];
      ts[tid] = (a != 0.0f) ? (-c / a) : INFINITY;
    }
    for (int j = tid; j < NI; j += 256) lb[j] = 0;
    __syncthreads();
    for (int ks = 2; ks <= 128; ks <<= 1) {
      for (int j = ks >> 1; j > 0; j >>= 1) {
        if (tid < 128) {
          int ixj = tid ^ j;
          if (ixj > tid) {
            float va = ts[tid], vb = ts[ixj];
            bool asc = ((tid & ks) == 0);
            if (asc ? (va > vb) : (va < vb)) { ts[tid] = vb; ts[ixj] = va; }
          }
        }
        __syncthreads();
      }
    }
    int e = (blockIdx.x - H0B)*256 + tid;
    if (e < NE) {
      float w = ew[eids[e]];
      int lo = 0, hi = 128;
      while (lo < hi) { int mid = (lo+hi)>>1; if (ts[mid] < w) lo = mid+1; else hi = mid; }
      jbuf[e] = lo; wbuf[e] = w;
      atomicAdd(&lb[lo], 1);
      atomicAdd(&counts[edst[e]], 1.0f);
    }
    __syncthreads();
    for (int j = tid; j < NI; j += 256) if (lb[j] > 0) atomicAdd(&bins[j], lb[j]);
  } else {
    // ---- weight-transpose path ----
    int p = (blockIdx.x - (H0B + CLB))*256 + tid;   // 0..9215
    float4 v;
    if (p < 1024) {
      int iq = p >> 6, o = p & 63;
      v.x = Wr_g[(4*iq+0)*64 + o];
      v.y = Wr_g[(4*iq+1)*64 + o];
      v.z = Wr_g[(4*iq+2)*64 + o];
      v.w = Wr_g[(4*iq+3)*64 + o];
    } else if (p < 4096) {
      int q = p - 1024; int g = q >> 10, iq = (q >> 6) & 15, o = q & 63;
      v = ((const float4*)Wih)[(g*64 + o)*16 + iq];
    } else if (p < 7168) {
      int q = p - 4096; int g = q >> 10, iq = (q >> 6) & 15, o = q & 63;
      v = ((const float4*)Whh)[(g*64 + o)*16 + iq];
    } else if (p < 8192) {
      int q = p - 7168; int iq = q >> 6, o = q & 63;
      v = ((const float4*)W1)[o*16 + iq];
    } else {
      int q = p - 8192; int iq = q >> 6, o = q & 63;
      v = ((const float4*)W2)[o*16 + iq];
    }
    wt[p] = v;
  }
}

// ---------------- K2: dst prefix-sum + live-interval header (single block, 1024 thr) ----
// PROVEN-BEST. Keep 1024 threads: latency-bound; 256-thread rewrite cost +32us (R8/R9).
__global__ __launch_bounds__(1024) void k_plan(const float* __restrict__ counts,
    const int* __restrict__ bins, int* __restrict__ doffs, int* __restrict__ dcur,
    int* __restrict__ hdr) {
  __shared__ int part[1024];
  __shared__ int m0s, m1s, nls;
  const int t = threadIdx.x;
  const int base = t*20;
  int s = 0;
  if (base < NTGT)
    for (int q = 0; q < 20 && base+q < NTGT; q++) s += (int)counts[base+q];
  part[t] = s;
  if (t == 0) { m0s = 999; m1s = 999; nls = 0; }
  __syncthreads();
  if (t < NI && bins[t] > 0) { atomicMin(&m0s, t); atomicAdd(&nls, 1); }
  for (int off = 1; off < 1024; off <<= 1) {
    int v = (t >= off) ? part[t-off] : 0;
    __syncthreads();
    part[t] += v;
    __syncthreads();
  }
  if (t < NI && bins[t] > 0 && t != m0s) atomicMin(&m1s, t);
  int run = part[t] - s;
  if (base < NTGT)
    for (int q = 0; q < 20 && base+q < NTGT; q++) {
      int c = (int)counts[base+q];
      doffs[base+q] = run; dcur[base+q] = run;
      run += c;
    }
  __syncthreads();
  if (t == 0) {
    doffs[NTGT] = NE;
    hdr[0] = m0s;
    hdr[1] = (m1s == 999) ? -1 : m1s;
    hdr[2] = nls;
  }
}

// ---------------- K3: fused mid = [M/C build (32 blocks) | dst-sort scatter (313)] ----------
__global__ __launch_bounds__(256) void k_mid(const float* __restrict__ A1,
    const float* __restrict__ c1, const float* __restrict__ A2, const float* __restrict__ c2,
    const int* __restrict__ hdr, float* __restrict__ MC,
    const int* __restrict__ esrc, const int* __restrict__ edst,
    const int* __restrict__ jbuf, const float* __restrict__ wbuf,
    int* __restrict__ dcur, int* __restrict__ psrc, float* __restrict__ pw) {
  const int tid = threadIdx.x;
  if (blockIdx.x < 32) {
    // ---- mc path: local T sort, representative, M/C chunk ----
    const int s = blockIdx.x >> 4;
    const int chunk = blockIdx.x & 15;
    const int j = (s == 0) ? hdr[0] : hdr[1];
    if (j < 0 || j > 128) return;    // uniform per block, before any barrier
    __shared__ float t[128], sk[128], uk[128];
    if (tid < 128) {
      float a = A1[tid], c = c1[tid];
      t[tid] = (a != 0.0f) ? (-c / a) : INFINITY;
    }
    __syncthreads();
    for (int ks = 2; ks <= 128; ks <<= 1) {
      for (int jj = ks >> 1; jj > 0; jj >>= 1) {
        if (tid < 128) {
          int ixj = tid ^ jj;
          if (ixj > tid) {
            float va = t[tid], vb = t[ixj];
            bool asc = ((tid & ks) == 0);
            if (asc ? (va > vb) : (va < vb)) { t[tid] = vb; t[ixj] = va; }
          }
        }
        __syncthreads();
      }
    }
    float lo = (j > 0)   ? t[j-1] : -INFINITY;
    float hi = (j < 128) ? t[j]   :  INFINITY;
    float rj;
    if (isinf(lo) && isinf(hi)) rj = 0.0f;
    else if (isinf(lo)) rj = hi - 1.0f;
    else if (isinf(hi)) rj = lo + 1.0f;
    else rj = 0.5f*(lo + hi);
    if (tid < 128) {
      float a = A1[tid], c = c1[tid];
      bool act = (rj*a + c) > 0.0f;
      sk[tid] = act ? a : 0.0f;
      uk[tid] = act ? c : 0.0f;
    }
    __syncthreads();
    float* M = MC + (size_t)s*8192;
    float* C = M + 4096;
    const int p = chunk*256 + tid;
    const float4* a2p = (const float4*)(A2 + (size_t)p*128);
    float accM = 0.0f, accC = 0.0f;
#pragma unroll 8
    for (int q = 0; q < 32; q++) {
      float4 v = a2p[q];
      int k4 = q*4;
      accM += sk[k4]*v.x + sk[k4+1]*v.y + sk[k4+2]*v.z + sk[k4+3]*v.w;
      accC += uk[k4]*v.x + uk[k4+1]*v.y + uk[k4+2]*v.z + uk[k4+3]*v.w;
    }
    M[p] = accM;
    C[p] = accC + c2[p];
  } else {
    // ---- sdst path ----
    int e = (blockIdx.x - 32)*256 + tid;
    if (e >= NE) return;
    int j0 = hdr[0];
    int d = edst[e];
    int pos = atomicAdd(&dcur[d], 1);
    int s = (jbuf[e] == j0) ? 0 : 1;
    psrc[pos] = esrc[e] | (s << 31);
    pw[pos] = wbuf[e];
  }
}

// ---------------- K4: FUSED uvagg + tail (PROVEN 107-108us, VGPR 32) --------------------
// Tile sweep complete: 4 dsts/wave optimal (8->110, 2->119). DO NOT replace the
// readlane/bpack broadcasts with LDS or VGPR temps: R4 and R7 both proved that variant
// hits a catastrophic scratch-spill cliff (400+ MB scratch traffic).
__global__ __launch_bounds__(256, 4) void k_ut(const int* __restrict__ doffs,
    const int* __restrict__ psrc, const float* __restrict__ pw,
    const float* __restrict__ MCg, const float* __restrict__ h0,
    const float4* __restrict__ wt, const float* __restrict__ bconv,
    const float* __restrict__ bih, const float* __restrict__ bhh,
    const float* __restrict__ b1, const float* __restrict__ b2,
    float* __restrict__ out) {
  __shared__ float rows_all[4][CHUNK*64];
  const int tid = threadIdx.x;
  const int lane = tid & 63;
  const int wid = __builtin_amdgcn_readfirstlane(tid >> 6);
  float* rows = &rows_all[wid][0];
  const int tb = __builtin_amdgcn_readfirstlane(blockIdx.x*16 + wid*4);
  const int o = lane;

  int b[5];
#pragma unroll
  for (int t = 0; t <= 4; t++) b[t] = doffs[tb + t];   // uniform -> s_load

  // issue tail-phase h rows early; in flight under the gather phase
  float h[4];
#pragma unroll
  for (int t = 0; t < 4; t++) h[t] = h0[(size_t)(tb+t)*64 + o];

  // ---------------- phase 1: U/V edge accumulate ----------------
  float U0[4], V0[4], U1[4], V1[4];
#pragma unroll
  for (int t = 0; t < 4; t++) { U0[t]=0.f; V0[t]=0.f; U1[t]=0.f; V1[t]=0.f; }

  const int e0 = b[0], e4 = b[4];
  for (int c0 = e0; c0 < e4; c0 += CHUNK) {
    const int n = min(CHUNK, e4 - c0);
    int   psv = psrc[c0 + (lane & (CHUNK-1))];
    float pwv = pw  [c0 + (lane & (CHUNK-1))];
    // one 256B global->LDS DMA per edge; PER-LANE global addr (+lane)
    for (int k = 0; k < n; k++) {
      int src = rli_(psv, k) & 0x7fffffff;
      gl_lds4(h0 + (size_t)src*64 + lane, rows + k*64);
    }
    __builtin_amdgcn_s_waitcnt(0);
#pragma unroll
    for (int t = 0; t < 4; t++) {
      int lo = b[t] > c0 ? b[t] : c0;
      int hi = b[t+1] < c0+n ? b[t+1] : c0+n;
      for (int pos = lo; pos < hi; pos++) {
        int k = pos - c0;
        int ps = rli_(psv, k);
        float w = rl_(pwv, k);
        float v = rows[k*64 + lane];
        if (ps >= 0) { U0[t] = fmaf(w, v, U0[t]); V0[t] += v; }
        else         { U1[t] = fmaf(w, v, U1[t]); V1[t] += v; }
      }
    }
  }
  float a[4];
#pragma unroll
  for (int t = 0; t < 4; t++) a[t] = 0.f;
#pragma unroll 4
  for (int i = 0; i < 64; i++) {
    float m0 = MCg[i*64 + lane];
    float c0 = MCg[4096 + i*64 + lane];
    float m1 = MCg[8192 + i*64 + lane];
    float cc1 = MCg[12288 + i*64 + lane];
#pragma unroll
    for (int t = 0; t < 4; t++) {
      a[t] = fmaf(rl_(U0[t], i), m0, a[t]);
      a[t] = fmaf(rl_(V0[t], i), c0, a[t]);
      a[t] = fmaf(rl_(U1[t], i), m1, a[t]);
      a[t] = fmaf(rl_(V1[t], i), cc1, a[t]);
    }
  }

  // ---------------- phase 2: conv-root + GRU(3) + MLP (R5 body) ----------------
  const float4* __restrict__ WrT  = wt;          // [16][64]
  const float4* __restrict__ WihT = wt + 1024;   // [3][16][64]
  const float4* __restrict__ WhhT = wt + 4096;   // [3][16][64]
  const float4* __restrict__ W1T  = wt + 7168;   // [16][64]
  const float4* __restrict__ W2T  = wt + 8192;   // [16][64]

  // ---- m = relu(a/c + h @ Wr + bc) ----
  float m[4];
  {
    v2f acc[4];
    const float bc = bconv[o];
#pragma unroll
    for (int t = 0; t < 4; t++) {
      float c = fmaxf((float)(b[t+1] - b[t]), 1.0f);
      acc[t].x = a[t] / c + bc;
      acc[t].y = 0.0f;
    }
    for (int iq = 0; iq < 16; iq++) {
      float4 wv = WrT[iq*64 + o];
      v2f wlo = { wv.x, wv.y }, whi = { wv.z, wv.w };
      int i4 = iq*4;
#pragma unroll
      for (int t = 0; t < 4; t++) {
        unsigned long long slo = bpack_(h[t], i4);
        unsigned long long shi = bpack_(h[t], i4+2);
        pkfma_(acc[t], slo, wlo);
        pkfma_(acc[t], shi, whi);
      }
    }
#pragma unroll
    for (int t = 0; t < 4; t++) m[t] = fmaxf(acc[t].x + acc[t].y, 0.0f);
  }

  // ---- gi = m @ Wih + (bih [+bhh folded for gates 0,1]) ----
  float gi0[4], gi1[4], gi2[4];
  {
    v2f a0[4], a1[4], a2[4];
#pragma unroll
    for (int t = 0; t < 4; t++) {
      a0[t].x = 0.0f; a0[t].y = 0.0f;
      a1[t].x = 0.0f; a1[t].y = 0.0f;
      a2[t].x = 0.0f; a2[t].y = 0.0f;
    }
    for (int iq = 0; iq < 16; iq++) {
      float4 w0 = WihT[iq*64 + o];
      float4 w1 = WihT[(16+iq)*64 + o];
      float4 w2 = WihT[(32+iq)*64 + o];
      v2f w0lo = { w0.x, w0.y }, w0hi = { w0.z, w0.w };
      v2f w1lo = { w1.x, w1.y }, w1hi = { w1.z, w1.w };
      v2f w2lo = { w2.x, w2.y }, w2hi = { w2.z, w2.w };
      int i4 = iq*4;
#pragma unroll
      for (int t = 0; t < 4; t++) {
        unsigned long long slo = bpack_(m[t], i4);
        unsigned long long shi = bpack_(m[t], i4+2);
        pkfma_(a0[t], slo, w0lo); pkfma_(a0[t], shi, w0hi);
        pkfma_(a1[t], slo, w1lo); pkfma_(a1[t], shi, w1hi);
        pkfma_(a2[t], slo, w2lo); pkfma_(a2[t], shi, w2hi);
      }
    }
    const float bi0 = bih[o]      + bhh[o];
    const float bi1 = bih[64+o]   + bhh[64+o];
    const float bi2 = bih[128+o];
#pragma unroll
    for (int t = 0; t < 4; t++) {
      gi0[t] = bi0 + a0[t].x + a0[t].y;
      gi1[t] = bi1 + a1[t].x + a1[t].y;
      gi2[t] = bi2 + a2[t].x + a2[t].y;
    }
  }

  // ---- GRU(3) ----
  const float bh2 = bhh[128+o];
#pragma unroll 1
  for (int step = 0; step < 3; step++) {
    v2f a0[4], a1[4], a2[4];
#pragma unroll
    for (int t = 0; t < 4; t++) {
      a0[t].x = 0.0f; a0[t].y = 0.0f;
      a1[t].x = 0.0f; a1[t].y = 0.0f;
      a2[t].x = 0.0f; a2[t].y = 0.0f;
    }
    for (int iq = 0; iq < 16; iq++) {
      float4 w0 = WhhT[iq*64 + o];
      float4 w1 = WhhT[(16+iq)*64 + o];
      float4 w2 = WhhT[(32+iq)*64 + o];
      v2f w0lo = { w0.x, w0.y }, w0hi = { w0.z, w0.w };
      v2f w1lo = { w1.x, w1.y }, w1hi = { w1.z, w1.w };
      v2f w2lo = { w2.x, w2.y }, w2hi = { w2.z, w2.w };
      int i4 = iq*4;
#pragma unroll
      for (int t = 0; t < 4; t++) {
        unsigned long long slo = bpack_(h[t], i4);
        unsigned long long shi = bpack_(h[t], i4+2);
        pkfma_(a0[t], slo, w0lo); pkfma_(a0[t], shi, w0hi);
        pkfma_(a1[t], slo, w1lo); pkfma_(a1[t], shi, w1hi);
        pkfma_(a2[t], slo, w2lo); pkfma_(a2[t], shi, w2hi);
      }
    }
#pragma unroll
    for (int t = 0; t < 4; t++) {
      float r = sigm_(gi0[t] + a0[t].x + a0[t].y);
      float z = sigm_(gi1[t] + a1[t].x + a1[t].y);
      float g2s = bh2 + a2[t].x + a2[t].y;
      float n = tanhf_(fmaf(r, g2s, gi2[t]));
      h[t] = fmaf(z, h[t] - n, n);
    }
  }

  // ---- o1 = relu(h @ W1 + b1) ----
  float o1[4];
  {
    v2f acc[4];
#pragma unroll
    for (int t = 0; t < 4; t++) { acc[t].x = 0.0f; acc[t].y = 0.0f; }
    for (int iq = 0; iq < 16; iq++) {
      float4 wv = W1T[iq*64 + o];
      v2f wlo = { wv.x, wv.y }, whi = { wv.z, wv.w };
      int i4 = iq*4;
#pragma unroll
      for (int t = 0; t < 4; t++) {
        unsigned long long slo = bpack_(h[t], i4);
        unsigned long long shi = bpack_(h[t], i4+2);
        pkfma_(acc[t], slo, wlo);
        pkfma_(acc[t], shi, whi);
      }
    }
    const float bb = b1[o];
#pragma unroll
    for (int t = 0; t < 4; t++) o1[t] = fmaxf(bb + acc[t].x + acc[t].y, 0.0f);
  }

  // ---- out = o1 @ W2 + b2 ----
  {
    v2f acc[4];
#pragma unroll
    for (int t = 0; t < 4; t++) { acc[t].x = 0.0f; acc[t].y = 0.0f; }
    for (int iq = 0; iq < 16; iq++) {
      float4 wv = W2T[iq*64 + o];
      v2f wlo = { wv.x, wv.y }, whi = { wv.z, wv.w };
      int i4 = iq*4;
#pragma unroll
      for (int t = 0; t < 4; t++) {
        unsigned long long slo = bpack_(o1[t], i4);
        unsigned long long shi = bpack_(o1[t], i4+2);
        pkfma_(acc[t], slo, wlo);
        pkfma_(acc[t], shi, whi);
      }
    }
    const float bb = b2[o];
#pragma unroll
    for (int t = 0; t < 4; t++) out[(size_t)(tb+t)*64 + o] = bb + acc[t].x + acc[t].y;
  }
}

extern "C" void kernel_launch(void* const* d_in, const int* in_sizes, int n_in,
                              void* d_out, int out_size, void* d_ws, size_t ws_size,
                              hipStream_t stream) {
  const float* x    = (const float*)d_in[0];
  const int*   esrc = (const int*)d_in[2];
  const int*   edst = (const int*)d_in[3];
  const int*   eids = (const int*)d_in[4];
  const float* ew   = (const float*)d_in[5];
  const float* W0   = (const float*)d_in[6];
  const float* b0   = (const float*)d_in[7];
  const float* A1   = (const float*)d_in[8];
  const float* c1   = (const float*)d_in[9];
  const float* A2   = (const float*)d_in[10];
  const float* c2   = (const float*)d_in[11];
  const float* Wr   = (const float*)d_in[12];
  const float* bcv  = (const float*)d_in[13];
  const float* Wih  = (const float*)d_in[14];
  const float* Whh  = (const float*)d_in[15];
  const float* bih  = (const float*)d_in[16];
  const float* bhh  = (const float*)d_in[17];
  const float* W1   = (const float*)d_in[18];
  const float* b1   = (const float*)d_in[19];
  const float* W2   = (const float*)d_in[20];
  const float* b2   = (const float*)d_in[21];

  char* ws = (char*)d_ws;
  float* h0    = (float*)(ws + H0_OFF);
  float* MC    = (float*)(ws + MC_OFF);
  float* cnts  = (float*)(ws + CNT_OFF);
  int*   bins  = (int*)(ws + BINS_OFF);
  int*   hdr   = (int*)(ws + HDR_OFF);
  int*   doffs = (int*)(ws + DOFF_OFF);
  int*   dcur  = (int*)(ws + DCUR_OFF);
  int*   jbuf  = (int*)(ws + JBUF_OFF);
  float* wbuf  = (float*)(ws + WBUF_OFF);
  int*   psrc  = (int*)(ws + PSRC_OFF);
  float* pw    = (float*)(ws + PW_OFF);
  float4* wt   = (float4*)(ws + WT_OFF);

  hipMemsetAsync(ws + CNT_OFF, 0, ZERO_BYTES, stream);
  k_front <<<H0B + CLB + WTB, 256, 0, stream>>>(x, W0, b0, h0, eids, edst, ew, A1, c1,
                                                jbuf, wbuf, bins, cnts,
                                                Wr, Wih, Whh, W1, W2, wt);
  k_plan  <<<1, 1024, 0, stream>>>(cnts, bins, doffs, dcur, hdr);
  k_mid   <<<32 + CLB, 256, 0, stream>>>(A1, c1, A2, c2, hdr, MC,
                                         esrc, edst, jbuf, wbuf, dcur, psrc, pw);
  k_ut    <<<1250, 256, 0, stream>>>(doffs, psrc, pw, MC, h0, wt, bcv,
                                     bih, bhh, b1, b2, (float*)d_out);
}